// Round 1
// baseline (691.782 us; speedup 1.0000x reference)
//
#include <hip/hip_runtime.h>
#include <math.h>

#define NAn 40000
#define NBn 40000
#define DIN 256
#define DOUT 256
#define NH 8
#define NC 32
#define NE 400000
#define CAP 64

__device__ __forceinline__ float leaky(float x) { return x > 0.f ? x : 0.2f * x; }
__device__ __forceinline__ float dot4(float4 a, float4 b) {
  return a.x * b.x + a.y * b.y + a.z * b.z + a.w * b.w;
}

// ---------------- GEMM: H = X @ W + bias  (fp32, 64x64x16 tile, 4x4/thread) ----
#define BM 64
#define BN 64
#define BK 16
__global__ __launch_bounds__(256) void gemm_bias(const float* __restrict__ X,
                                                 const float* __restrict__ W,
                                                 const float* __restrict__ bias,
                                                 float* __restrict__ Hout) {
  __shared__ float As[BK][BM + 4];
  __shared__ float Bs[BK][BN + 4];
  const int tid = threadIdx.x;
  const int tx = tid & 15, ty = tid >> 4;
  const int row0 = blockIdx.x * BM, col0 = blockIdx.y * BN;
  const int lm = tid >> 2;        // 0..63  (row within A tile)
  const int lk = (tid & 3) * 4;   // 0,4,8,12
  const int wk = tid >> 4;        // 0..15  (k row within B tile)
  const int wn = (tid & 15) * 4;  // 0..60
  float acc[4][4] = {};
  for (int k0 = 0; k0 < DIN; k0 += BK) {
    float4 xa = *(const float4*)&X[(size_t)(row0 + lm) * DIN + k0 + lk];
    float4 wb = *(const float4*)&W[(size_t)(k0 + wk) * DOUT + col0 + wn];
    As[lk + 0][lm] = xa.x;
    As[lk + 1][lm] = xa.y;
    As[lk + 2][lm] = xa.z;
    As[lk + 3][lm] = xa.w;
    *(float4*)&Bs[wk][wn] = wb;
    __syncthreads();
#pragma unroll
    for (int kk = 0; kk < BK; ++kk) {
      float4 av = *(const float4*)&As[kk][ty * 4];
      float4 bv = *(const float4*)&Bs[kk][tx * 4];
      float a[4] = {av.x, av.y, av.z, av.w};
      float b[4] = {bv.x, bv.y, bv.z, bv.w};
#pragma unroll
      for (int i = 0; i < 4; ++i)
#pragma unroll
        for (int j = 0; j < 4; ++j) acc[i][j] += a[i] * b[j];
    }
    __syncthreads();
  }
  float4 bb = *(const float4*)&bias[col0 + tx * 4];
#pragma unroll
  for (int i = 0; i < 4; ++i) {
    float4 o = {acc[i][0] + bb.x, acc[i][1] + bb.y, acc[i][2] + bb.z, acc[i][3] + bb.w};
    *(float4*)&Hout[(size_t)(row0 + ty * 4 + i) * DOUT + col0 + tx * 4] = o;
  }
}

// ------------- per-(node,head) attention scalars -------------
// A nodes need: al0 = h.attn_l[0], ar1 = h.attn_r[1], al2 = h.attn_l[2], ar2 = h.attn_r[2]
__global__ void alphas_A(const float* __restrict__ h, const float* __restrict__ attn_l,
                         const float* __restrict__ attn_r, float* __restrict__ al0,
                         float* __restrict__ ar1, float* __restrict__ al2,
                         float* __restrict__ ar2) {
  int idx = blockIdx.x * blockDim.x + threadIdx.x;  // node*8 + head
  if (idx >= NAn * NH) return;
  int head = idx & 7;
  const float4* h4 = (const float4*)(h + (size_t)idx * NC);  // node*256 + head*32
  const float4* l0 = (const float4*)(attn_l + 0 * DOUT + head * NC);
  const float4* r1 = (const float4*)(attn_r + 1 * DOUT + head * NC);
  const float4* l2 = (const float4*)(attn_l + 2 * DOUT + head * NC);
  const float4* r2 = (const float4*)(attn_r + 2 * DOUT + head * NC);
  float s0 = 0, s1 = 0, s2 = 0, s3 = 0;
#pragma unroll
  for (int q = 0; q < 8; ++q) {
    float4 hv = h4[q];
    s0 += dot4(hv, l0[q]);
    s1 += dot4(hv, r1[q]);
    s2 += dot4(hv, l2[q]);
    s3 += dot4(hv, r2[q]);
  }
  al0[idx] = s0;
  ar1[idx] = s1;
  al2[idx] = s2;
  ar2[idx] = s3;
}

// B nodes need: ar0 = h.attn_r[0], al1 = h.attn_l[1]
__global__ void alphas_B(const float* __restrict__ h, const float* __restrict__ attn_l,
                         const float* __restrict__ attn_r, float* __restrict__ ar0,
                         float* __restrict__ al1) {
  int idx = blockIdx.x * blockDim.x + threadIdx.x;
  if (idx >= NBn * NH) return;
  int head = idx & 7;
  const float4* h4 = (const float4*)(h + (size_t)idx * NC);
  const float4* r0 = (const float4*)(attn_r + 0 * DOUT + head * NC);
  const float4* l1 = (const float4*)(attn_l + 1 * DOUT + head * NC);
  float s0 = 0, s1 = 0;
#pragma unroll
  for (int q = 0; q < 8; ++q) {
    float4 hv = h4[q];
    s0 += dot4(hv, r0[q]);
    s1 += dot4(hv, l1[q]);
  }
  ar0[idx] = s0;
  al1[idx] = s1;
}

// ------------- bucket edges by destination (capacity CAP per dst) -------------
__global__ void build_csr(const int* __restrict__ edge, int* __restrict__ cnt,
                          int* __restrict__ slots) {
  int i = blockIdx.x * blockDim.x + threadIdx.x;
  if (i >= NE) return;
  int src = edge[i];
  int dst = edge[NE + i];
  int pos = atomicAdd(&cnt[dst], 1);
  if (pos < CAP) slots[(size_t)dst * CAP + pos] = src;
}

// ------------- gather-side GAT aggregation: one wave per dst node -------------
__global__ __launch_bounds__(256) void gat_agg(const int* __restrict__ cnt,
                                               const int* __restrict__ slots,
                                               const float* __restrict__ al,
                                               const float* __restrict__ ar,
                                               const float* __restrict__ hsrc,
                                               float* __restrict__ outp, int ndst) {
  int wave = threadIdx.x >> 6, lane = threadIdx.x & 63;
  int dst = blockIdx.x * 4 + wave;
  if (dst >= ndst) return;
  int head = lane >> 3;  // element index within row = lane*4 -> head = lane/8
  int deg = cnt[dst];
  if (deg > CAP) deg = CAP;
  const int* sl = slots + (size_t)dst * CAP;
  float arh = ar[dst * NH + head];
  float m = -1e30f;
  for (int j = 0; j < deg; ++j) {
    int s = sl[j];
    m = fmaxf(m, leaky(al[s * NH + head] + arh));
  }
  float denom = 0.f;
  float4 acc = {0.f, 0.f, 0.f, 0.f};
  for (int j = 0; j < deg; ++j) {
    int s = sl[j];
    float e = leaky(al[s * NH + head] + arh);
    float ex = __expf(e - m);
    denom += ex;
    float4 hv = *(const float4*)&hsrc[(size_t)s * DOUT + lane * 4];
    acc.x += ex * hv.x;
    acc.y += ex * hv.y;
    acc.z += ex * hv.z;
    acc.w += ex * hv.w;
  }
  float inv = deg > 0 ? 1.f / denom : 0.f;
  float4 o = {acc.x * inv, acc.y * inv, acc.z * inv, acc.w * inv};
  *(float4*)&outp[(size_t)dst * DOUT + lane * 4] = o;
}

// ------------- beta combine (relation softmax) + ReLU -------------
__global__ __launch_bounds__(256) void combine_A(const float* __restrict__ h,
                                                 const float* __restrict__ r0,  // rel_ba
                                                 const float* __restrict__ r1,  // rel_aa
                                                 const float* __restrict__ rl,
                                                 const float* __restrict__ rr,
                                                 float* __restrict__ outp) {
  int wave = threadIdx.x >> 6, lane = threadIdx.x & 63;
  int node = blockIdx.x * 4 + wave;
  if (node >= NAn) return;
  size_t off = (size_t)node * DOUT + lane * 4;
  float4 hv = *(const float4*)&h[off];
  float4 e0 = *(const float4*)&r0[off];
  float4 e1 = *(const float4*)&r1[off];
  float4 rlv = *(const float4*)&rl[lane * 4];
  float4 rrv = *(const float4*)&rr[lane * 4];
  float pbl = dot4(hv, rlv);
  float p0 = dot4(e0, rrv), p1 = dot4(e1, rrv), p2 = dot4(hv, rrv);
#pragma unroll
  for (int d = 1; d < 8; d <<= 1) {
    pbl += __shfl_xor(pbl, d);
    p0 += __shfl_xor(p0, d);
    p1 += __shfl_xor(p1, d);
    p2 += __shfl_xor(p2, d);
  }
  float b0 = leaky(pbl + p0), b1 = leaky(pbl + p1), b2 = leaky(pbl + p2);
  float mx = fmaxf(b0, fmaxf(b1, b2));
  float w0 = __expf(b0 - mx), w1 = __expf(b1 - mx), w2 = __expf(b2 - mx);
  float inv = 1.f / (w0 + w1 + w2);
  w0 *= inv;
  w1 *= inv;
  w2 *= inv;
  float4 o = {fmaxf(0.f, e0.x * w0 + e1.x * w1 + hv.x * w2),
              fmaxf(0.f, e0.y * w0 + e1.y * w1 + hv.y * w2),
              fmaxf(0.f, e0.z * w0 + e1.z * w1 + hv.z * w2),
              fmaxf(0.f, e0.w * w0 + e1.w * w1 + hv.w * w2)};
  *(float4*)&outp[off] = o;
}

__global__ __launch_bounds__(256) void combine_B(const float* __restrict__ h,
                                                 const float* __restrict__ r0,  // rel_ab
                                                 const float* __restrict__ rl,
                                                 const float* __restrict__ rr,
                                                 float* __restrict__ outp) {
  int wave = threadIdx.x >> 6, lane = threadIdx.x & 63;
  int node = blockIdx.x * 4 + wave;
  if (node >= NBn) return;
  size_t off = (size_t)node * DOUT + lane * 4;
  float4 hv = *(const float4*)&h[off];
  float4 e0 = *(const float4*)&r0[off];
  float4 rlv = *(const float4*)&rl[lane * 4];
  float4 rrv = *(const float4*)&rr[lane * 4];
  float pbl = dot4(hv, rlv);
  float p0 = dot4(e0, rrv), p1 = dot4(hv, rrv);
#pragma unroll
  for (int d = 1; d < 8; d <<= 1) {
    pbl += __shfl_xor(pbl, d);
    p0 += __shfl_xor(p0, d);
    p1 += __shfl_xor(p1, d);
  }
  float b0 = leaky(pbl + p0), b1 = leaky(pbl + p1);
  float mx = fmaxf(b0, b1);
  float w0 = __expf(b0 - mx), w1 = __expf(b1 - mx);
  float inv = 1.f / (w0 + w1);
  w0 *= inv;
  w1 *= inv;
  float4 o = {fmaxf(0.f, e0.x * w0 + hv.x * w1), fmaxf(0.f, e0.y * w0 + hv.y * w1),
              fmaxf(0.f, e0.z * w0 + hv.z * w1), fmaxf(0.f, e0.w * w0 + hv.w * w1)};
  *(float4*)&outp[off] = o;
}

extern "C" void kernel_launch(void* const* d_in, const int* in_sizes, int n_in, void* d_out,
                              int out_size, void* d_ws, size_t ws_size, hipStream_t stream) {
  const float* xA = (const float*)d_in[0];
  const float* xB = (const float*)d_in[1];
  const int* e_ab = (const int*)d_in[2];  // src in A, dst in B
  const int* e_ba = (const int*)d_in[3];  // src in B, dst in A
  const int* e_aa = (const int*)d_in[4];  // src in A, dst in A
  const float* WA = (const float*)d_in[5];
  const float* bA = (const float*)d_in[6];
  const float* WB = (const float*)d_in[7];
  const float* bB = (const float*)d_in[8];
  const float* attn_l = (const float*)d_in[9];
  const float* attn_r = (const float*)d_in[10];
  const float* rlA = (const float*)d_in[11];
  const float* rrA = (const float*)d_in[12];
  const float* rlB = (const float*)d_in[13];
  const float* rrB = (const float*)d_in[14];
  float* out = (float*)d_out;

  char* p = (char*)d_ws;
  auto alloc = [&](size_t bytes) -> char* {
    char* r = p;
    p += (bytes + 255) & ~(size_t)255;
    return r;
  };
  float* hA = (float*)alloc((size_t)NAn * DOUT * 4);
  float* hB = (float*)alloc((size_t)NBn * DOUT * 4);
  float* relba = (float*)alloc((size_t)NAn * DOUT * 4);
  float* relaa = (float*)alloc((size_t)NAn * DOUT * 4);
  float* relab = (float*)alloc((size_t)NBn * DOUT * 4);
  float* al0 = (float*)alloc((size_t)NAn * NH * 4);
  float* ar1 = (float*)alloc((size_t)NAn * NH * 4);
  float* al2 = (float*)alloc((size_t)NAn * NH * 4);
  float* ar2 = (float*)alloc((size_t)NAn * NH * 4);
  float* ar0 = (float*)alloc((size_t)NBn * NH * 4);
  float* al1 = (float*)alloc((size_t)NBn * NH * 4);
  int* cnts = (int*)alloc((size_t)3 * NAn * 4);  // [ba | aa | ab]
  int* cnt_ba = cnts;
  int* cnt_aa = cnts + NAn;
  int* cnt_ab = cnts + 2 * NAn;
  int* slots_ba = (int*)alloc((size_t)NAn * CAP * 4);
  int* slots_aa = (int*)alloc((size_t)NAn * CAP * 4);
  int* slots_ab = (int*)alloc((size_t)NBn * CAP * 4);

  hipMemsetAsync(cnts, 0, (size_t)3 * NAn * 4, stream);

  dim3 gb(NAn / BM, DOUT / BN);
  gemm_bias<<<gb, 256, 0, stream>>>(xA, WA, bA, hA);
  gemm_bias<<<gb, 256, 0, stream>>>(xB, WB, bB, hB);

  alphas_A<<<(NAn * NH + 255) / 256, 256, 0, stream>>>(hA, attn_l, attn_r, al0, ar1, al2, ar2);
  alphas_B<<<(NBn * NH + 255) / 256, 256, 0, stream>>>(hB, attn_l, attn_r, ar0, al1);

  int ebl = (NE + 255) / 256;
  build_csr<<<ebl, 256, 0, stream>>>(e_ba, cnt_ba, slots_ba);
  build_csr<<<ebl, 256, 0, stream>>>(e_aa, cnt_aa, slots_aa);
  build_csr<<<ebl, 256, 0, stream>>>(e_ab, cnt_ab, slots_ab);

  // metapath 1: B->A, metapath 2: A->A, metapath 0: A->B
  gat_agg<<<(NAn + 3) / 4, 256, 0, stream>>>(cnt_ba, slots_ba, al1, ar1, hB, relba, NAn);
  gat_agg<<<(NAn + 3) / 4, 256, 0, stream>>>(cnt_aa, slots_aa, al2, ar2, hA, relaa, NAn);
  gat_agg<<<(NBn + 3) / 4, 256, 0, stream>>>(cnt_ab, slots_ab, al0, ar0, hA, relab, NBn);

  combine_A<<<(NAn + 3) / 4, 256, 0, stream>>>(hA, relba, relaa, rlA, rrA, out);
  combine_B<<<(NBn + 3) / 4, 256, 0, stream>>>(hB, relab, rlB, rrB, out + (size_t)NAn * DOUT);
}

// Round 2
// 553.735 us; speedup vs baseline: 1.2493x; 1.2493x over previous
//
#include <hip/hip_runtime.h>
#include <math.h>

#define NAn 40000
#define NBn 40000
#define DIN 256
#define DOUT 256
#define NH 8
#define NC 32
#define NE 400000
#define CAP 64

typedef __attribute__((ext_vector_type(8))) short short8;
typedef __attribute__((ext_vector_type(4))) float floatx4;

__device__ __forceinline__ float leaky(float x) { return x > 0.f ? x : 0.2f * x; }
__device__ __forceinline__ float dot4(float4 a, float4 b) {
  return a.x * b.x + a.y * b.y + a.z * b.z + a.w * b.w;
}
// round-to-nearest-even bf16, returned as hi-aligned fp32 bits
__device__ __forceinline__ unsigned bf16_rne_bits(float x) {
  unsigned u = __float_as_uint(x);
  unsigned r = u + 0x7fffu + ((u >> 16) & 1u);
  return r & 0xffff0000u;
}
__device__ __forceinline__ float4 bf4(uint2 u) {
  float4 f;
  f.x = __uint_as_float(u.x << 16);
  f.y = __uint_as_float(u.x & 0xffff0000u);
  f.z = __uint_as_float(u.y << 16);
  f.w = __uint_as_float(u.y & 0xffff0000u);
  return f;
}

// ---- W fp32 -> swizzled bf16 hi/lo B-fragments -------------------------------
// frag index t = (kt*16 + nt)*64 + lane ; lane holds B[k][n], n = nt*16+(lane&15),
// k = kt*32 + (lane>>4)*8 + j  (j = 0..7 contiguous shorts)
__global__ void wswz(const float* __restrict__ W, short8* __restrict__ hi,
                     short8* __restrict__ lo) {
  int t = blockIdx.x * blockDim.x + threadIdx.x;
  if (t >= 8 * 16 * 64) return;
  int kt = t >> 10, nt = (t >> 6) & 15, l = t & 63;
  int n = nt * 16 + (l & 15);
  int kb = kt * 32 + (l >> 4) * 8;
  short8 h8, l8;
#pragma unroll
  for (int j = 0; j < 8; ++j) {
    float w = W[(size_t)(kb + j) * DOUT + n];
    unsigned hb = bf16_rne_bits(w);
    h8[j] = (short)(hb >> 16);
    float rem = w - __uint_as_float(hb);
    l8[j] = (short)(bf16_rne_bits(rem) >> 16);
  }
  hi[t] = h8;
  lo[t] = l8;
}

// ---- MFMA GEMM: H = X @ W + b, split-bf16 (3 mfma), no LDS -------------------
// block = 256 thr = 4 waves; wave computes 16 rows x 256 cols (16 tiles of 16x16)
__global__ __launch_bounds__(256) void gemm_mfma(const float* __restrict__ X,
                                                 const short8* __restrict__ Whi,
                                                 const short8* __restrict__ Wlo,
                                                 const float* __restrict__ bias,
                                                 float* __restrict__ Hout,
                                                 unsigned* __restrict__ Hbf) {
  const int lane = threadIdx.x & 63, wave = threadIdx.x >> 6;
  const int row0 = blockIdx.x * 64 + wave * 16;
  const int col16 = lane & 15, quad = lane >> 4;
  floatx4 acc[16];
#pragma unroll
  for (int i = 0; i < 16; ++i) acc[i] = (floatx4){0.f, 0.f, 0.f, 0.f};
  const float4* xp = (const float4*)(X + (size_t)(row0 + col16) * DIN + quad * 8);
  for (int kt = 0; kt < 8; ++kt) {
    float4 x0 = xp[kt * 8];
    float4 x1 = xp[kt * 8 + 1];
    float xv[8] = {x0.x, x0.y, x0.z, x0.w, x1.x, x1.y, x1.z, x1.w};
    short8 ahi, alo;
#pragma unroll
    for (int j = 0; j < 8; ++j) {
      unsigned hb = bf16_rne_bits(xv[j]);
      ahi[j] = (short)(hb >> 16);
      float rem = xv[j] - __uint_as_float(hb);
      alo[j] = (short)(bf16_rne_bits(rem) >> 16);
    }
    const short8* bh = Whi + (size_t)kt * 1024 + lane;
    const short8* bl = Wlo + (size_t)kt * 1024 + lane;
#pragma unroll
    for (int nt = 0; nt < 16; ++nt) {
      short8 bhv = bh[nt * 64];
      short8 blv = bl[nt * 64];
      acc[nt] = __builtin_amdgcn_mfma_f32_16x16x32_bf16(ahi, bhv, acc[nt], 0, 0, 0);
      acc[nt] = __builtin_amdgcn_mfma_f32_16x16x32_bf16(alo, bhv, acc[nt], 0, 0, 0);
      acc[nt] = __builtin_amdgcn_mfma_f32_16x16x32_bf16(ahi, blv, acc[nt], 0, 0, 0);
    }
  }
  // epilogue: C/D mapping col = lane&15, row = quad*4 + r
#pragma unroll
  for (int nt = 0; nt < 16; ++nt) {
    float bcol = bias[nt * 16 + col16];
#pragma unroll
    for (int r = 0; r < 4; ++r) {
      int row = row0 + quad * 4 + r;
      float v = acc[nt][r] + bcol;
      Hout[(size_t)row * DOUT + nt * 16 + col16] = v;
      float vp = __shfl_xor(v, 1);  // partner col (odd)
      if ((lane & 1) == 0) {
        unsigned p = (bf16_rne_bits(v) >> 16) | bf16_rne_bits(vp);
        Hbf[(size_t)row * 128 + nt * 8 + (col16 >> 1)] = p;
      }
    }
  }
}

// ---- per-(node,head) attention scalars ---------------------------------------
__global__ void alphas_A(const float* __restrict__ h, const float* __restrict__ attn_l,
                         const float* __restrict__ attn_r, float* __restrict__ al0,
                         float* __restrict__ ar1, float* __restrict__ al2,
                         float* __restrict__ ar2) {
  int idx = blockIdx.x * blockDim.x + threadIdx.x;
  if (idx >= NAn * NH) return;
  int head = idx & 7;
  const float4* h4 = (const float4*)(h + (size_t)idx * NC);
  const float4* l0 = (const float4*)(attn_l + 0 * DOUT + head * NC);
  const float4* r1 = (const float4*)(attn_r + 1 * DOUT + head * NC);
  const float4* l2 = (const float4*)(attn_l + 2 * DOUT + head * NC);
  const float4* r2 = (const float4*)(attn_r + 2 * DOUT + head * NC);
  float s0 = 0, s1 = 0, s2 = 0, s3 = 0;
#pragma unroll
  for (int q = 0; q < 8; ++q) {
    float4 hv = h4[q];
    s0 += dot4(hv, l0[q]);
    s1 += dot4(hv, r1[q]);
    s2 += dot4(hv, l2[q]);
    s3 += dot4(hv, r2[q]);
  }
  al0[idx] = s0;
  ar1[idx] = s1;
  al2[idx] = s2;
  ar2[idx] = s3;
}

__global__ void alphas_B(const float* __restrict__ h, const float* __restrict__ attn_l,
                         const float* __restrict__ attn_r, float* __restrict__ ar0,
                         float* __restrict__ al1) {
  int idx = blockIdx.x * blockDim.x + threadIdx.x;
  if (idx >= NBn * NH) return;
  int head = idx & 7;
  const float4* h4 = (const float4*)(h + (size_t)idx * NC);
  const float4* r0 = (const float4*)(attn_r + 0 * DOUT + head * NC);
  const float4* l1 = (const float4*)(attn_l + 1 * DOUT + head * NC);
  float s0 = 0, s1 = 0;
#pragma unroll
  for (int q = 0; q < 8; ++q) {
    float4 hv = h4[q];
    s0 += dot4(hv, r0[q]);
    s1 += dot4(hv, l1[q]);
  }
  ar0[idx] = s0;
  al1[idx] = s1;
}

// ---- bucket all three edge lists by destination ------------------------------
__global__ void build_csr3(const int* __restrict__ e_ba, const int* __restrict__ e_aa,
                           const int* __restrict__ e_ab, int* __restrict__ cnt_ba,
                           int* __restrict__ cnt_aa, int* __restrict__ cnt_ab,
                           int* __restrict__ sl_ba, int* __restrict__ sl_aa,
                           int* __restrict__ sl_ab) {
  int i = blockIdx.x * blockDim.x + threadIdx.x;
  if (i >= 3 * NE) return;
  const int* e;
  int* cnt;
  int* sl;
  int k = i;
  if (i < NE) {
    e = e_ba; cnt = cnt_ba; sl = sl_ba;
  } else if (i < 2 * NE) {
    e = e_aa; cnt = cnt_aa; sl = sl_aa; k = i - NE;
  } else {
    e = e_ab; cnt = cnt_ab; sl = sl_ab; k = i - 2 * NE;
  }
  int src = e[k];
  int dst = e[NE + k];
  int pos = atomicAdd(&cnt[dst], 1);
  if (pos < CAP) sl[(size_t)dst * CAP + pos] = src;
}

// ---- one relation's GAT message for one dst (one wave) -----------------------
// lane j<deg owns edge j (all 8 heads); softmax denom via shfl; weights via LDS;
// message loop: 1 independent dwordx2 bf16 row-gather per edge per lane.
__device__ __forceinline__ float4 gat_gather(int dst, int wave, int lane, int head,
                                             const int* __restrict__ cnt,
                                             const int* __restrict__ slots,
                                             const float* __restrict__ al,
                                             const float* __restrict__ ar,
                                             const uint2* __restrict__ hbf,
                                             int lds_slot[][64], float lds_ex[][64][8]) {
  float4 macc = {0.f, 0.f, 0.f, 0.f};
  int deg = cnt[dst];
  if (deg > CAP) deg = CAP;
  if (deg == 0) return macc;
  float4 arl = *(const float4*)(ar + (size_t)dst * 8);
  float4 arh = *(const float4*)(ar + (size_t)dst * 8 + 4);
  float arv[8] = {arl.x, arl.y, arl.z, arl.w, arh.x, arh.y, arh.z, arh.w};
  float ex[8];
  __threadfence_block();  // order vs previous phase's LDS reads
  if (lane < deg) {
    int s = slots[(size_t)dst * CAP + lane];
    float4 a0 = *(const float4*)(al + (size_t)s * 8);
    float4 a1 = *(const float4*)(al + (size_t)s * 8 + 4);
    float alv[8] = {a0.x, a0.y, a0.z, a0.w, a1.x, a1.y, a1.z, a1.w};
    lds_slot[wave][lane] = s;
#pragma unroll
    for (int h = 0; h < 8; ++h) {
      ex[h] = __expf(leaky(alv[h] + arv[h]));  // max-shift dropped: |logit| small
      lds_ex[wave][lane][h] = ex[h];
    }
  } else {
#pragma unroll
    for (int h = 0; h < 8; ++h) ex[h] = 0.f;
  }
  float den[8];
#pragma unroll
  for (int h = 0; h < 8; ++h) {
    float v = ex[h];
#pragma unroll
    for (int d = 1; d < 64; d <<= 1) v += __shfl_xor(v, d);
    den[h] = v;
  }
  __threadfence_block();  // LDS writes visible before reads
  for (int j = 0; j < deg; ++j) {
    int sj = lds_slot[wave][j];
    float w = lds_ex[wave][j][head];
    float4 f = bf4(hbf[(size_t)sj * 64 + lane]);
    macc.x += w * f.x;
    macc.y += w * f.y;
    macc.z += w * f.z;
    macc.w += w * f.w;
  }
  float inv = 1.f / den[head];
  macc.x *= inv;
  macc.y *= inv;
  macc.z *= inv;
  macc.w *= inv;
  return macc;
}

// ---- fused: aggregate both A-relations + beta combine + ReLU -----------------
__global__ __launch_bounds__(256) void agg_combine_A(
    const int* __restrict__ cnt_ba, const int* __restrict__ sl_ba,
    const float* __restrict__ al1, const float* __restrict__ ar1,
    const int* __restrict__ cnt_aa, const int* __restrict__ sl_aa,
    const float* __restrict__ al2, const float* __restrict__ ar2,
    const uint2* __restrict__ hBbf, const uint2* __restrict__ hAbf,
    const float* __restrict__ hA, const float* __restrict__ rl,
    const float* __restrict__ rr, float* __restrict__ outp) {
  __shared__ int lds_slot[4][64];
  __shared__ float lds_ex[4][64][8];
  int wave = threadIdx.x >> 6, lane = threadIdx.x & 63, head = lane >> 3;
  int dst = blockIdx.x * 4 + wave;  // NAn % 4 == 0, always valid
  float4 m0 = gat_gather(dst, wave, lane, head, cnt_ba, sl_ba, al1, ar1, hBbf, lds_slot, lds_ex);
  float4 m1 = gat_gather(dst, wave, lane, head, cnt_aa, sl_aa, al2, ar2, hAbf, lds_slot, lds_ex);
  float4 hv = *(const float4*)(hA + (size_t)dst * DOUT + lane * 4);
  float4 rlv = ((const float4*)rl)[lane];
  float4 rrv = ((const float4*)rr)[lane];
  float pbl = dot4(hv, rlv);
  float p0 = dot4(m0, rrv), p1 = dot4(m1, rrv), p2 = dot4(hv, rrv);
#pragma unroll
  for (int d = 1; d < 8; d <<= 1) {
    pbl += __shfl_xor(pbl, d);
    p0 += __shfl_xor(p0, d);
    p1 += __shfl_xor(p1, d);
    p2 += __shfl_xor(p2, d);
  }
  float b0 = leaky(pbl + p0), b1 = leaky(pbl + p1), b2 = leaky(pbl + p2);
  float mx = fmaxf(b0, fmaxf(b1, b2));
  float w0 = __expf(b0 - mx), w1 = __expf(b1 - mx), w2 = __expf(b2 - mx);
  float inv = 1.f / (w0 + w1 + w2);
  w0 *= inv;
  w1 *= inv;
  w2 *= inv;
  float4 o = {fmaxf(0.f, m0.x * w0 + m1.x * w1 + hv.x * w2),
              fmaxf(0.f, m0.y * w0 + m1.y * w1 + hv.y * w2),
              fmaxf(0.f, m0.z * w0 + m1.z * w1 + hv.z * w2),
              fmaxf(0.f, m0.w * w0 + m1.w * w1 + hv.w * w2)};
  *(float4*)(outp + (size_t)dst * DOUT + lane * 4) = o;
}

__global__ __launch_bounds__(256) void agg_combine_B(
    const int* __restrict__ cnt_ab, const int* __restrict__ sl_ab,
    const float* __restrict__ al0, const float* __restrict__ ar0,
    const uint2* __restrict__ hAbf, const float* __restrict__ hB,
    const float* __restrict__ rl, const float* __restrict__ rr,
    float* __restrict__ outp) {
  __shared__ int lds_slot[4][64];
  __shared__ float lds_ex[4][64][8];
  int wave = threadIdx.x >> 6, lane = threadIdx.x & 63, head = lane >> 3;
  int dst = blockIdx.x * 4 + wave;
  float4 m0 = gat_gather(dst, wave, lane, head, cnt_ab, sl_ab, al0, ar0, hAbf, lds_slot, lds_ex);
  float4 hv = *(const float4*)(hB + (size_t)dst * DOUT + lane * 4);
  float4 rlv = ((const float4*)rl)[lane];
  float4 rrv = ((const float4*)rr)[lane];
  float pbl = dot4(hv, rlv);
  float p0 = dot4(m0, rrv), p1 = dot4(hv, rrv);
#pragma unroll
  for (int d = 1; d < 8; d <<= 1) {
    pbl += __shfl_xor(pbl, d);
    p0 += __shfl_xor(p0, d);
    p1 += __shfl_xor(p1, d);
  }
  float b0 = leaky(pbl + p0), b1 = leaky(pbl + p1);
  float mx = fmaxf(b0, b1);
  float w0 = __expf(b0 - mx), w1 = __expf(b1 - mx);
  float inv = 1.f / (w0 + w1);
  w0 *= inv;
  w1 *= inv;
  float4 o = {fmaxf(0.f, m0.x * w0 + hv.x * w1), fmaxf(0.f, m0.y * w0 + hv.y * w1),
              fmaxf(0.f, m0.z * w0 + hv.z * w1), fmaxf(0.f, m0.w * w0 + hv.w * w1)};
  *(float4*)(outp + (size_t)dst * DOUT + lane * 4) = o;
}

extern "C" void kernel_launch(void* const* d_in, const int* in_sizes, int n_in, void* d_out,
                              int out_size, void* d_ws, size_t ws_size, hipStream_t stream) {
  const float* xA = (const float*)d_in[0];
  const float* xB = (const float*)d_in[1];
  const int* e_ab = (const int*)d_in[2];
  const int* e_ba = (const int*)d_in[3];
  const int* e_aa = (const int*)d_in[4];
  const float* WA = (const float*)d_in[5];
  const float* bA = (const float*)d_in[6];
  const float* WB = (const float*)d_in[7];
  const float* bB = (const float*)d_in[8];
  const float* attn_l = (const float*)d_in[9];
  const float* attn_r = (const float*)d_in[10];
  const float* rlA = (const float*)d_in[11];
  const float* rrA = (const float*)d_in[12];
  const float* rlB = (const float*)d_in[13];
  const float* rrB = (const float*)d_in[14];
  float* out = (float*)d_out;

  char* p = (char*)d_ws;
  auto alloc = [&](size_t bytes) -> char* {
    char* r = p;
    p += (bytes + 255) & ~(size_t)255;
    return r;
  };
  float* hA = (float*)alloc((size_t)NAn * DOUT * 4);
  float* hB = (float*)alloc((size_t)NBn * DOUT * 4);
  unsigned* hAbf = (unsigned*)alloc((size_t)NAn * DOUT * 2);
  unsigned* hBbf = (unsigned*)alloc((size_t)NBn * DOUT * 2);
  float* al0 = (float*)alloc((size_t)NAn * NH * 4);
  float* ar1 = (float*)alloc((size_t)NAn * NH * 4);
  float* al2 = (float*)alloc((size_t)NAn * NH * 4);
  float* ar2 = (float*)alloc((size_t)NAn * NH * 4);
  float* ar0 = (float*)alloc((size_t)NBn * NH * 4);
  float* al1 = (float*)alloc((size_t)NBn * NH * 4);
  short8* WAhi = (short8*)alloc((size_t)8192 * 16);
  short8* WAlo = (short8*)alloc((size_t)8192 * 16);
  short8* WBhi = (short8*)alloc((size_t)8192 * 16);
  short8* WBlo = (short8*)alloc((size_t)8192 * 16);
  int* cnts = (int*)alloc((size_t)3 * NAn * 4);
  int* cnt_ba = cnts;
  int* cnt_aa = cnts + NAn;
  int* cnt_ab = cnts + 2 * NAn;
  int* slots_ba = (int*)alloc((size_t)NAn * CAP * 4);
  int* slots_aa = (int*)alloc((size_t)NAn * CAP * 4);
  int* slots_ab = (int*)alloc((size_t)NBn * CAP * 4);

  hipMemsetAsync(cnts, 0, (size_t)3 * NAn * 4, stream);

  wswz<<<32, 256, 0, stream>>>(WA, WAhi, WAlo);
  wswz<<<32, 256, 0, stream>>>(WB, WBhi, WBlo);

  gemm_mfma<<<NAn / 64, 256, 0, stream>>>(xA, WAhi, WAlo, bA, hA, hAbf);
  gemm_mfma<<<NBn / 64, 256, 0, stream>>>(xB, WBhi, WBlo, bB, hB, hBbf);

  alphas_A<<<(NAn * NH + 255) / 256, 256, 0, stream>>>(hA, attn_l, attn_r, al0, ar1, al2, ar2);
  alphas_B<<<(NBn * NH + 255) / 256, 256, 0, stream>>>(hB, attn_l, attn_r, ar0, al1);

  build_csr3<<<(3 * NE + 255) / 256, 256, 0, stream>>>(e_ba, e_aa, e_ab, cnt_ba, cnt_aa,
                                                       cnt_ab, slots_ba, slots_aa, slots_ab);

  agg_combine_A<<<NAn / 4, 256, 0, stream>>>(cnt_ba, slots_ba, al1, ar1, cnt_aa, slots_aa,
                                             al2, ar2, (const uint2*)hBbf, (const uint2*)hAbf,
                                             hA, rlA, rrA, out);
  agg_combine_B<<<NBn / 4, 256, 0, stream>>>(cnt_ab, slots_ab, al0, ar0, (const uint2*)hAbf,
                                             hB, rlB, rrB, out + (size_t)NAn * DOUT);
}

// Round 3
// 476.465 us; speedup vs baseline: 1.4519x; 1.1622x over previous
//
#include <hip/hip_runtime.h>
#include <math.h>

#define NAn 40000
#define NBn 40000
#define DIN 256
#define DOUT 256
#define NH 8
#define NC 32
#define NE 400000
#define CAP 64

typedef __attribute__((ext_vector_type(8))) short short8;
typedef __attribute__((ext_vector_type(4))) float floatx4;

__device__ __forceinline__ float leaky(float x) { return x > 0.f ? x : 0.2f * x; }
__device__ __forceinline__ float dot4(float4 a, float4 b) {
  return a.x * b.x + a.y * b.y + a.z * b.z + a.w * b.w;
}
__device__ __forceinline__ unsigned bf16_rne_bits(float x) {
  unsigned u = __float_as_uint(x);
  unsigned r = u + 0x7fffu + ((u >> 16) & 1u);
  return r & 0xffff0000u;
}
__device__ __forceinline__ float4 bf4(uint2 u) {
  float4 f;
  f.x = __uint_as_float(u.x << 16);
  f.y = __uint_as_float(u.x & 0xffff0000u);
  f.z = __uint_as_float(u.y << 16);
  f.w = __uint_as_float(u.y & 0xffff0000u);
  return f;
}
__device__ __forceinline__ void bf8(uint4 u, float* f) {
  f[0] = __uint_as_float(u.x << 16);
  f[1] = __uint_as_float(u.x & 0xffff0000u);
  f[2] = __uint_as_float(u.y << 16);
  f[3] = __uint_as_float(u.y & 0xffff0000u);
  f[4] = __uint_as_float(u.z << 16);
  f[5] = __uint_as_float(u.z & 0xffff0000u);
  f[6] = __uint_as_float(u.w << 16);
  f[7] = __uint_as_float(u.w & 0xffff0000u);
}

// ---- W fp32 -> swizzled bf16 hi/lo B-fragments (both matrices, one launch) ---
__global__ void wswz(const float* __restrict__ WA, const float* __restrict__ WB,
                     short8* __restrict__ hiA, short8* __restrict__ loA,
                     short8* __restrict__ hiB, short8* __restrict__ loB) {
  int t = blockIdx.x * blockDim.x + threadIdx.x;
  const float* W;
  short8 *hi, *lo;
  if (t < 8192) {
    W = WA; hi = hiA; lo = loA;
  } else {
    t -= 8192;
    if (t >= 8192) return;
    W = WB; hi = hiB; lo = loB;
  }
  int kt = t >> 10, nt = (t >> 6) & 15, l = t & 63;
  int n = nt * 16 + (l & 15);
  int kb = kt * 32 + (l >> 4) * 8;
  short8 h8, l8;
#pragma unroll
  for (int j = 0; j < 8; ++j) {
    float w = W[(size_t)(kb + j) * DOUT + n];
    unsigned hb = bf16_rne_bits(w);
    h8[j] = (short)(hb >> 16);
    float rem = w - __uint_as_float(hb);
    l8[j] = (short)(bf16_rne_bits(rem) >> 16);
  }
  hi[t] = h8;
  lo[t] = l8;
}

// ---- MFMA GEMM: Hbf = bf16(X @ W + b), split-bf16 (3 mfma), no LDS ----------
__global__ __launch_bounds__(256) void gemm_mfma(
    const float* __restrict__ XA, const float* __restrict__ XB,
    const short8* __restrict__ WAhi, const short8* __restrict__ WAlo,
    const short8* __restrict__ WBhi, const short8* __restrict__ WBlo,
    const float* __restrict__ bA, const float* __restrict__ bB,
    unsigned* __restrict__ HAbf, unsigned* __restrict__ HBbf) {
  int blk = blockIdx.x;
  const float* X;
  const short8 *Wh, *Wl;
  const float* bias;
  unsigned* Hbf;
  if (blk < NAn / 64) {
    X = XA; Wh = WAhi; Wl = WAlo; bias = bA; Hbf = HAbf;
  } else {
    blk -= NAn / 64;
    X = XB; Wh = WBhi; Wl = WBlo; bias = bB; Hbf = HBbf;
  }
  const int lane = threadIdx.x & 63, wave = threadIdx.x >> 6;
  const int row0 = blk * 64 + wave * 16;
  const int col16 = lane & 15, quad = lane >> 4;
  floatx4 acc[16];
#pragma unroll
  for (int i = 0; i < 16; ++i) acc[i] = (floatx4){0.f, 0.f, 0.f, 0.f};
  const float4* xp = (const float4*)(X + (size_t)(row0 + col16) * DIN + quad * 8);
  for (int kt = 0; kt < 8; ++kt) {
    float4 x0 = xp[kt * 8];
    float4 x1 = xp[kt * 8 + 1];
    float xv[8] = {x0.x, x0.y, x0.z, x0.w, x1.x, x1.y, x1.z, x1.w};
    short8 ahi, alo;
#pragma unroll
    for (int j = 0; j < 8; ++j) {
      unsigned hb = bf16_rne_bits(xv[j]);
      ahi[j] = (short)(hb >> 16);
      float rem = xv[j] - __uint_as_float(hb);
      alo[j] = (short)(bf16_rne_bits(rem) >> 16);
    }
    const short8* bh = Wh + (size_t)kt * 1024 + lane;
    const short8* bl = Wl + (size_t)kt * 1024 + lane;
#pragma unroll
    for (int nt = 0; nt < 16; ++nt) {
      short8 bhv = bh[nt * 64];
      short8 blv = bl[nt * 64];
      acc[nt] = __builtin_amdgcn_mfma_f32_16x16x32_bf16(ahi, bhv, acc[nt], 0, 0, 0);
      acc[nt] = __builtin_amdgcn_mfma_f32_16x16x32_bf16(alo, bhv, acc[nt], 0, 0, 0);
      acc[nt] = __builtin_amdgcn_mfma_f32_16x16x32_bf16(ahi, blv, acc[nt], 0, 0, 0);
    }
  }
#pragma unroll
  for (int nt = 0; nt < 16; ++nt) {
    float bcol = bias[nt * 16 + col16];
#pragma unroll
    for (int r = 0; r < 4; ++r) {
      int row = row0 + quad * 4 + r;
      float v = acc[nt][r] + bcol;
      float vp = __shfl_xor(v, 1);
      if ((lane & 1) == 0) {
        unsigned p = (bf16_rne_bits(v) >> 16) | bf16_rne_bits(vp);
        Hbf[(size_t)row * 128 + nt * 8 + (col16 >> 1)] = p;
      }
    }
  }
}

// ---- per-(node,head) attention scalars, bf16 h, both node sets --------------
__global__ void alphas(const uint2* __restrict__ hAbf, const uint2* __restrict__ hBbf,
                       const float* __restrict__ attn_l, const float* __restrict__ attn_r,
                       float* __restrict__ al0, float* __restrict__ ar1,
                       float* __restrict__ al2, float* __restrict__ ar2,
                       float* __restrict__ ar0, float* __restrict__ al1) {
  int idx = blockIdx.x * blockDim.x + threadIdx.x;
  if (idx >= (NAn + NBn) * NH) return;
  bool isA = idx < NAn * NH;
  int k = isA ? idx : idx - NAn * NH;
  int head = k & 7;
  const uint2* h8 = (isA ? hAbf : hBbf) + (size_t)k * 8;  // 8*uint2 = 32 bf16
  if (isA) {
    const float4* l0 = (const float4*)(attn_l + 0 * DOUT + head * NC);
    const float4* r1 = (const float4*)(attn_r + 1 * DOUT + head * NC);
    const float4* l2 = (const float4*)(attn_l + 2 * DOUT + head * NC);
    const float4* r2 = (const float4*)(attn_r + 2 * DOUT + head * NC);
    float s0 = 0, s1 = 0, s2 = 0, s3 = 0;
#pragma unroll
    for (int q = 0; q < 8; ++q) {
      float4 hv = bf4(h8[q]);
      s0 += dot4(hv, l0[q]);
      s1 += dot4(hv, r1[q]);
      s2 += dot4(hv, l2[q]);
      s3 += dot4(hv, r2[q]);
    }
    al0[k] = s0;
    ar1[k] = s1;
    al2[k] = s2;
    ar2[k] = s3;
  } else {
    const float4* r0 = (const float4*)(attn_r + 0 * DOUT + head * NC);
    const float4* l1 = (const float4*)(attn_l + 1 * DOUT + head * NC);
    float s0 = 0, s1 = 0;
#pragma unroll
    for (int q = 0; q < 8; ++q) {
      float4 hv = bf4(h8[q]);
      s0 += dot4(hv, r0[q]);
      s1 += dot4(hv, l1[q]);
    }
    ar0[k] = s0;
    al1[k] = s1;
  }
}

// ---- bucket all three edge lists by destination ------------------------------
__global__ void build_csr3(const int* __restrict__ e_ba, const int* __restrict__ e_aa,
                           const int* __restrict__ e_ab, int* __restrict__ cnt_ba,
                           int* __restrict__ cnt_aa, int* __restrict__ cnt_ab,
                           int* __restrict__ sl_ba, int* __restrict__ sl_aa,
                           int* __restrict__ sl_ab) {
  int i = blockIdx.x * blockDim.x + threadIdx.x;
  if (i >= 3 * NE) return;
  const int* e;
  int* cnt;
  int* sl;
  int k = i;
  if (i < NE) {
    e = e_ba; cnt = cnt_ba; sl = sl_ba;
  } else if (i < 2 * NE) {
    e = e_aa; cnt = cnt_aa; sl = sl_aa; k = i - NE;
  } else {
    e = e_ab; cnt = cnt_ab; sl = sl_ab; k = i - 2 * NE;
  }
  int src = e[k];
  int dst = e[NE + k];
  int pos = atomicAdd(&cnt[dst], 1);
  if (pos < CAP) sl[(size_t)dst * CAP + pos] = src;
}

// ---- one relation's normalized GAT message (one wave, 2 edges/iter) ---------
// half h = lane>>5 owns edge stream; 32 lanes x uint4 = one 512B bf16 row.
// Denominator accumulated inside the message loop (no shuffle reduction).
__device__ __forceinline__ void gat2(int dst, int wave, int lane, int h, int sub, int head,
                                     const int* __restrict__ cnt,
                                     const int* __restrict__ slots,
                                     const float* __restrict__ al,
                                     const float* __restrict__ ar,
                                     const uint4* __restrict__ hbf,
                                     int lds_slot[4][64], float lds_ex[4][512],
                                     float acc[8]) {
#pragma unroll
  for (int k = 0; k < 8; ++k) acc[k] = 0.f;
  int deg = cnt[dst];
  if (deg > CAP) deg = CAP;
  if (deg == 0) return;
  __threadfence_block();  // order vs previous relation's LDS reads
  if (lane < deg) {
    int s = slots[(size_t)dst * CAP + lane];
    lds_slot[wave][lane] = s;
    float4 a0 = *(const float4*)(al + (size_t)s * 8);
    float4 a1 = *(const float4*)(al + (size_t)s * 8 + 4);
    float4 r0 = *(const float4*)(ar + (size_t)dst * 8);
    float4 r1 = *(const float4*)(ar + (size_t)dst * 8 + 4);
    float* exq = &lds_ex[wave][lane * 8];
    exq[0] = __expf(leaky(a0.x + r0.x));
    exq[1] = __expf(leaky(a0.y + r0.y));
    exq[2] = __expf(leaky(a0.z + r0.z));
    exq[3] = __expf(leaky(a0.w + r0.w));
    exq[4] = __expf(leaky(a1.x + r1.x));
    exq[5] = __expf(leaky(a1.y + r1.y));
    exq[6] = __expf(leaky(a1.z + r1.z));
    exq[7] = __expf(leaky(a1.w + r1.w));
  }
  __threadfence_block();  // LDS writes visible before reads
  float den = 0.f;
  int iters = (deg + 1) >> 1;
  for (int it = 0; it < iters; ++it) {
    int j = it * 2 + h;
    if (j < deg) {
      int sj = lds_slot[wave][j];
      float w = lds_ex[wave][j * 8 + head];
      uint4 u = hbf[(size_t)sj * 32 + sub];
      den += w;
      float f[8];
      bf8(u, f);
#pragma unroll
      for (int k = 0; k < 8; ++k) acc[k] += w * f[k];
    }
  }
#pragma unroll
  for (int k = 0; k < 8; ++k) acc[k] += __shfl_xor(acc[k], 32);
  den += __shfl_xor(den, 32);
  float inv = 1.f / den;  // deg>0 => den>0
#pragma unroll
  for (int k = 0; k < 8; ++k) acc[k] *= inv;
}

// ---- fused: all relations + beta combine + ReLU, A and B node sets ----------
__global__ __launch_bounds__(256) void agg_combine(
    const int* __restrict__ cnt_ba, const int* __restrict__ sl_ba,
    const float* __restrict__ al1, const float* __restrict__ ar1,
    const int* __restrict__ cnt_aa, const int* __restrict__ sl_aa,
    const float* __restrict__ al2, const float* __restrict__ ar2,
    const int* __restrict__ cnt_ab, const int* __restrict__ sl_ab,
    const float* __restrict__ al0, const float* __restrict__ ar0,
    const uint4* __restrict__ hAbf, const uint4* __restrict__ hBbf,
    const float* __restrict__ rlA, const float* __restrict__ rrA,
    const float* __restrict__ rlB, const float* __restrict__ rrB,
    float* __restrict__ outp) {
  __shared__ int lds_slot[4][64];
  __shared__ float lds_ex[4][512];
  int wave = threadIdx.x >> 6, lane = threadIdx.x & 63;
  int h = lane >> 5, sub = lane & 31, head = sub >> 2;
  bool isA = blockIdx.x < (NAn / 4);
  int dst = (isA ? blockIdx.x : blockIdx.x - NAn / 4) * 4 + wave;
  float m0[8], hv[8], o[8];
  if (isA) {
    float m1[8];
    gat2(dst, wave, lane, h, sub, head, cnt_ba, sl_ba, al1, ar1, hBbf, lds_slot, lds_ex, m0);
    gat2(dst, wave, lane, h, sub, head, cnt_aa, sl_aa, al2, ar2, hAbf, lds_slot, lds_ex, m1);
    uint4 us = hAbf[(size_t)dst * 32 + sub];
    bf8(us, hv);
    const float4* rl4 = (const float4*)rlA;
    const float4* rr4 = (const float4*)rrA;
    float4 rl0 = rl4[sub * 2], rl1 = rl4[sub * 2 + 1];
    float4 rr0 = rr4[sub * 2], rr1 = rr4[sub * 2 + 1];
    float rl8[8] = {rl0.x, rl0.y, rl0.z, rl0.w, rl1.x, rl1.y, rl1.z, rl1.w};
    float rr8[8] = {rr0.x, rr0.y, rr0.z, rr0.w, rr1.x, rr1.y, rr1.z, rr1.w};
    float pbl = 0, p0 = 0, p1 = 0, p2 = 0;
#pragma unroll
    for (int k = 0; k < 8; ++k) {
      pbl += hv[k] * rl8[k];
      p0 += m0[k] * rr8[k];
      p1 += m1[k] * rr8[k];
      p2 += hv[k] * rr8[k];
    }
#pragma unroll
    for (int d = 1; d < 4; d <<= 1) {  // reduce over the 4 lanes of this head
      pbl += __shfl_xor(pbl, d);
      p0 += __shfl_xor(p0, d);
      p1 += __shfl_xor(p1, d);
      p2 += __shfl_xor(p2, d);
    }
    float b0 = leaky(pbl + p0), b1 = leaky(pbl + p1), b2 = leaky(pbl + p2);
    float mx = fmaxf(b0, fmaxf(b1, b2));
    float w0 = __expf(b0 - mx), w1 = __expf(b1 - mx), w2 = __expf(b2 - mx);
    float inv = 1.f / (w0 + w1 + w2);
    w0 *= inv; w1 *= inv; w2 *= inv;
#pragma unroll
    for (int k = 0; k < 8; ++k)
      o[k] = fmaxf(0.f, m0[k] * w0 + m1[k] * w1 + hv[k] * w2);
  } else {
    gat2(dst, wave, lane, h, sub, head, cnt_ab, sl_ab, al0, ar0, hAbf, lds_slot, lds_ex, m0);
    uint4 us = hBbf[(size_t)dst * 32 + sub];
    bf8(us, hv);
    const float4* rl4 = (const float4*)rlB;
    const float4* rr4 = (const float4*)rrB;
    float4 rl0 = rl4[sub * 2], rl1 = rl4[sub * 2 + 1];
    float4 rr0 = rr4[sub * 2], rr1 = rr4[sub * 2 + 1];
    float rl8[8] = {rl0.x, rl0.y, rl0.z, rl0.w, rl1.x, rl1.y, rl1.z, rl1.w};
    float rr8[8] = {rr0.x, rr0.y, rr0.z, rr0.w, rr1.x, rr1.y, rr1.z, rr1.w};
    float pbl = 0, p0 = 0, p1 = 0;
#pragma unroll
    for (int k = 0; k < 8; ++k) {
      pbl += hv[k] * rl8[k];
      p0 += m0[k] * rr8[k];
      p1 += hv[k] * rr8[k];
    }
#pragma unroll
    for (int d = 1; d < 4; d <<= 1) {
      pbl += __shfl_xor(pbl, d);
      p0 += __shfl_xor(p0, d);
      p1 += __shfl_xor(p1, d);
    }
    float b0 = leaky(pbl + p0), b1 = leaky(pbl + p1);
    float mx = fmaxf(b0, b1);
    float w0 = __expf(b0 - mx), w1 = __expf(b1 - mx);
    float inv = 1.f / (w0 + w1);
    w0 *= inv; w1 *= inv;
#pragma unroll
    for (int k = 0; k < 8; ++k) o[k] = fmaxf(0.f, m0[k] * w0 + hv[k] * w1);
  }
  float* orow = outp + (size_t)(isA ? dst : NAn + dst) * DOUT + sub * 8;
  if (h == 0) {
    *(float4*)orow = (float4){o[0], o[1], o[2], o[3]};
    *(float4*)(orow + 4) = (float4){o[4], o[5], o[6], o[7]};
  }
}

extern "C" void kernel_launch(void* const* d_in, const int* in_sizes, int n_in, void* d_out,
                              int out_size, void* d_ws, size_t ws_size, hipStream_t stream) {
  const float* xA = (const float*)d_in[0];
  const float* xB = (const float*)d_in[1];
  const int* e_ab = (const int*)d_in[2];
  const int* e_ba = (const int*)d_in[3];
  const int* e_aa = (const int*)d_in[4];
  const float* WA = (const float*)d_in[5];
  const float* bA = (const float*)d_in[6];
  const float* WB = (const float*)d_in[7];
  const float* bB = (const float*)d_in[8];
  const float* attn_l = (const float*)d_in[9];
  const float* attn_r = (const float*)d_in[10];
  const float* rlA = (const float*)d_in[11];
  const float* rrA = (const float*)d_in[12];
  const float* rlB = (const float*)d_in[13];
  const float* rrB = (const float*)d_in[14];
  float* out = (float*)d_out;

  char* p = (char*)d_ws;
  auto alloc = [&](size_t bytes) -> char* {
    char* r = p;
    p += (bytes + 255) & ~(size_t)255;
    return r;
  };
  unsigned* hAbf = (unsigned*)alloc((size_t)NAn * DOUT * 2);
  unsigned* hBbf = (unsigned*)alloc((size_t)NBn * DOUT * 2);
  float* al0 = (float*)alloc((size_t)NAn * NH * 4);
  float* ar1 = (float*)alloc((size_t)NAn * NH * 4);
  float* al2 = (float*)alloc((size_t)NAn * NH * 4);
  float* ar2 = (float*)alloc((size_t)NAn * NH * 4);
  float* ar0 = (float*)alloc((size_t)NBn * NH * 4);
  float* al1 = (float*)alloc((size_t)NBn * NH * 4);
  short8* WAhi = (short8*)alloc((size_t)8192 * 16);
  short8* WAlo = (short8*)alloc((size_t)8192 * 16);
  short8* WBhi = (short8*)alloc((size_t)8192 * 16);
  short8* WBlo = (short8*)alloc((size_t)8192 * 16);
  int* cnts = (int*)alloc((size_t)3 * NAn * 4);
  int* cnt_ba = cnts;
  int* cnt_aa = cnts + NAn;
  int* cnt_ab = cnts + 2 * NAn;
  int* slots_ba = (int*)alloc((size_t)NAn * CAP * 4);
  int* slots_aa = (int*)alloc((size_t)NAn * CAP * 4);
  int* slots_ab = (int*)alloc((size_t)NBn * CAP * 4);

  hipMemsetAsync(cnts, 0, (size_t)3 * NAn * 4, stream);

  wswz<<<64, 256, 0, stream>>>(WA, WB, WAhi, WAlo, WBhi, WBlo);
  build_csr3<<<(3 * NE + 255) / 256, 256, 0, stream>>>(e_ba, e_aa, e_ab, cnt_ba, cnt_aa,
                                                       cnt_ab, slots_ba, slots_aa, slots_ab);
  gemm_mfma<<<(NAn + NBn) / 64, 256, 0, stream>>>(xA, xB, WAhi, WAlo, WBhi, WBlo, bA, bB,
                                                  hAbf, hBbf);
  alphas<<<((NAn + NBn) * NH + 255) / 256, 256, 0, stream>>>(
      (const uint2*)hAbf, (const uint2*)hBbf, attn_l, attn_r, al0, ar1, al2, ar2, ar0, al1);
  agg_combine<<<(NAn + NBn) / 4, 256, 0, stream>>>(
      cnt_ba, slots_ba, al1, ar1, cnt_aa, slots_aa, al2, ar2, cnt_ab, slots_ab, al0, ar0,
      (const uint4*)hAbf, (const uint4*)hBbf, rlA, rrA, rlB, rrB, out);
}

// Round 4
// 439.698 us; speedup vs baseline: 1.5733x; 1.0836x over previous
//
#include <hip/hip_runtime.h>
#include <math.h>

#define NAn 40000
#define NBn 40000
#define DIN 256
#define DOUT 256
#define NH 8
#define NC 32
#define NE 400000
#define CAP 64

typedef __attribute__((ext_vector_type(8))) short short8;
typedef __attribute__((ext_vector_type(4))) float floatx4;

__device__ __forceinline__ float leaky(float x) { return x > 0.f ? x : 0.2f * x; }
__device__ __forceinline__ float dot4(float4 a, float4 b) {
  return a.x * b.x + a.y * b.y + a.z * b.z + a.w * b.w;
}
__device__ __forceinline__ unsigned bf16_rne_bits(float x) {
  unsigned u = __float_as_uint(x);
  unsigned r = u + 0x7fffu + ((u >> 16) & 1u);
  return r & 0xffff0000u;
}
__device__ __forceinline__ float4 bf4(uint2 u) {
  float4 f;
  f.x = __uint_as_float(u.x << 16);
  f.y = __uint_as_float(u.x & 0xffff0000u);
  f.z = __uint_as_float(u.y << 16);
  f.w = __uint_as_float(u.y & 0xffff0000u);
  return f;
}
__device__ __forceinline__ void bf8(uint4 u, float* f) {
  f[0] = __uint_as_float(u.x << 16);
  f[1] = __uint_as_float(u.x & 0xffff0000u);
  f[2] = __uint_as_float(u.y << 16);
  f[3] = __uint_as_float(u.y & 0xffff0000u);
  f[4] = __uint_as_float(u.z << 16);
  f[5] = __uint_as_float(u.z & 0xffff0000u);
  f[6] = __uint_as_float(u.w << 16);
  f[7] = __uint_as_float(u.w & 0xffff0000u);
}

// ---- W fp32 -> swizzled bf16 B-fragments (hi only; both matrices) -----------
// frag t = kt*1024 + nt*64 + lane; lane holds B[k][n], n = nt*16+(lane&15),
// k = kt*32 + (lane>>4)*8 + j
__global__ void wswz(const float* __restrict__ WA, const float* __restrict__ WB,
                     short8* __restrict__ hiA, short8* __restrict__ hiB) {
  int t = blockIdx.x * blockDim.x + threadIdx.x;
  const float* W;
  short8* hi;
  if (t < 8192) {
    W = WA; hi = hiA;
  } else {
    t -= 8192;
    if (t >= 8192) return;
    W = WB; hi = hiB;
  }
  int kt = t >> 10, nt = (t >> 6) & 15, l = t & 63;
  int n = nt * 16 + (l & 15);
  int kb = kt * 32 + (l >> 4) * 8;
  short8 h8;
#pragma unroll
  for (int j = 0; j < 8; ++j) {
    float w = W[(size_t)(kb + j) * DOUT + n];
    h8[j] = (short)(bf16_rne_bits(w) >> 16);
  }
  hi[t] = h8;
}

// ---- MFMA GEMM: Hbf = bf16(X @ W + b) -------------------------------------
// X split hi/lo (2 mfma, W plain bf16). Block = 4 waves, 64 rows; B-tile for
// each kt (16 KB) staged in LDS (double-buffered) and shared by all 4 waves.
__global__ __launch_bounds__(256) void gemm_mfma(
    const float* __restrict__ XA, const float* __restrict__ XB,
    const short8* __restrict__ WAhi, const short8* __restrict__ WBhi,
    const float* __restrict__ bA, const float* __restrict__ bB,
    unsigned* __restrict__ HAbf, unsigned* __restrict__ HBbf) {
  __shared__ short8 bfrag[2][1024];  // 2 x 16 KB
  int blk = blockIdx.x;
  const float* X;
  const short8* Wh;
  const float* bias;
  unsigned* Hbf;
  if (blk < NAn / 64) {
    X = XA; Wh = WAhi; bias = bA; Hbf = HAbf;
  } else {
    blk -= NAn / 64;
    X = XB; Wh = WBhi; bias = bB; Hbf = HBbf;
  }
  const int tid = threadIdx.x;
  const int lane = tid & 63, wave = tid >> 6;
  const int row0 = blk * 64 + wave * 16;
  const int col16 = lane & 15, quad = lane >> 4;

  floatx4 acc[16];
#pragma unroll
  for (int i = 0; i < 16; ++i) acc[i] = (floatx4){0.f, 0.f, 0.f, 0.f};

  // X pointer: row m = row0+col16, cols kt*32 + quad*8 (.. +8)
  const float4* xp = (const float4*)(X + (size_t)(row0 + col16) * DIN) + quad * 2;

  uint4 pre[4];
  const uint4* wsrc = (const uint4*)Wh;
#pragma unroll
  for (int c = 0; c < 4; ++c) pre[c] = wsrc[c * 256 + tid];  // kt=0 tile
  {
    uint4* d = (uint4*)&bfrag[0][0];
#pragma unroll
    for (int c = 0; c < 4; ++c) d[c * 256 + tid] = pre[c];
  }
  __syncthreads();

  for (int kt = 0; kt < 8; ++kt) {
    if (kt < 7) {
      const uint4* s = wsrc + (size_t)(kt + 1) * 1024;
#pragma unroll
      for (int c = 0; c < 4; ++c) pre[c] = s[c * 256 + tid];
    }
    // A-fragment conversion (split bf16)
    float4 x0 = xp[kt * 8];
    float4 x1 = xp[kt * 8 + 1];
    float xv[8] = {x0.x, x0.y, x0.z, x0.w, x1.x, x1.y, x1.z, x1.w};
    short8 ahi, alo;
#pragma unroll
    for (int j = 0; j < 8; ++j) {
      unsigned hb = bf16_rne_bits(xv[j]);
      ahi[j] = (short)(hb >> 16);
      float rem = xv[j] - __uint_as_float(hb);
      alo[j] = (short)(bf16_rne_bits(rem) >> 16);
    }
    const short8* bp = &bfrag[kt & 1][0];
#pragma unroll
    for (int nt = 0; nt < 16; ++nt) {
      short8 bv = bp[nt * 64 + lane];  // ds_read_b128
      acc[nt] = __builtin_amdgcn_mfma_f32_16x16x32_bf16(ahi, bv, acc[nt], 0, 0, 0);
      acc[nt] = __builtin_amdgcn_mfma_f32_16x16x32_bf16(alo, bv, acc[nt], 0, 0, 0);
    }
    if (kt < 7) {
      uint4* d = (uint4*)&bfrag[(kt + 1) & 1][0];
#pragma unroll
      for (int c = 0; c < 4; ++c) d[c * 256 + tid] = pre[c];
    }
    __syncthreads();
  }
  // epilogue: C/D mapping col = lane&15, row = quad*4 + r
#pragma unroll
  for (int nt = 0; nt < 16; ++nt) {
    float bcol = bias[nt * 16 + col16];
#pragma unroll
    for (int r = 0; r < 4; ++r) {
      int row = row0 + quad * 4 + r;
      float v = acc[nt][r] + bcol;
      float vp = __shfl_xor(v, 1);
      if ((lane & 1) == 0) {
        unsigned p = (bf16_rne_bits(v) >> 16) | bf16_rne_bits(vp);
        Hbf[(size_t)row * 128 + nt * 8 + (col16 >> 1)] = p;
      }
    }
  }
}

// ---- per-(node,head) attention scalars, bf16 h, both node sets --------------
__global__ void alphas(const uint2* __restrict__ hAbf, const uint2* __restrict__ hBbf,
                       const float* __restrict__ attn_l, const float* __restrict__ attn_r,
                       float* __restrict__ al0, float* __restrict__ ar1,
                       float* __restrict__ al2, float* __restrict__ ar2,
                       float* __restrict__ ar0, float* __restrict__ al1) {
  int idx = blockIdx.x * blockDim.x + threadIdx.x;
  if (idx >= (NAn + NBn) * NH) return;
  bool isA = idx < NAn * NH;
  int k = isA ? idx : idx - NAn * NH;
  int head = k & 7;
  const uint2* h8 = (isA ? hAbf : hBbf) + (size_t)k * 8;
  if (isA) {
    const float4* l0 = (const float4*)(attn_l + 0 * DOUT + head * NC);
    const float4* r1 = (const float4*)(attn_r + 1 * DOUT + head * NC);
    const float4* l2 = (const float4*)(attn_l + 2 * DOUT + head * NC);
    const float4* r2 = (const float4*)(attn_r + 2 * DOUT + head * NC);
    float s0 = 0, s1 = 0, s2 = 0, s3 = 0;
#pragma unroll
    for (int q = 0; q < 8; ++q) {
      float4 hv = bf4(h8[q]);
      s0 += dot4(hv, l0[q]);
      s1 += dot4(hv, r1[q]);
      s2 += dot4(hv, l2[q]);
      s3 += dot4(hv, r2[q]);
    }
    al0[k] = s0;
    ar1[k] = s1;
    al2[k] = s2;
    ar2[k] = s3;
  } else {
    const float4* r0 = (const float4*)(attn_r + 0 * DOUT + head * NC);
    const float4* l1 = (const float4*)(attn_l + 1 * DOUT + head * NC);
    float s0 = 0, s1 = 0;
#pragma unroll
    for (int q = 0; q < 8; ++q) {
      float4 hv = bf4(h8[q]);
      s0 += dot4(hv, r0[q]);
      s1 += dot4(hv, l1[q]);
    }
    ar0[k] = s0;
    al1[k] = s1;
  }
}

// ---- bucket all three edge lists by destination ------------------------------
__global__ void build_csr3(const int* __restrict__ e_ba, const int* __restrict__ e_aa,
                           const int* __restrict__ e_ab, int* __restrict__ cnt_ba,
                           int* __restrict__ cnt_aa, int* __restrict__ cnt_ab,
                           int* __restrict__ sl_ba, int* __restrict__ sl_aa,
                           int* __restrict__ sl_ab) {
  int i = blockIdx.x * blockDim.x + threadIdx.x;
  if (i >= 3 * NE) return;
  const int* e;
  int* cnt;
  int* sl;
  int k = i;
  if (i < NE) {
    e = e_ba; cnt = cnt_ba; sl = sl_ba;
  } else if (i < 2 * NE) {
    e = e_aa; cnt = cnt_aa; sl = sl_aa; k = i - NE;
  } else {
    e = e_ab; cnt = cnt_ab; sl = sl_ab; k = i - 2 * NE;
  }
  int src = e[k];
  int dst = e[NE + k];
  int pos = atomicAdd(&cnt[dst], 1);
  if (pos < CAP) sl[(size_t)dst * CAP + pos] = src;
}

// ---- one relation's normalized GAT message (one wave, 2 edges/iter) ---------
__device__ __forceinline__ void gat2(int dst, int wave, int lane, int h, int sub, int head,
                                     const int* __restrict__ cnt,
                                     const int* __restrict__ slots,
                                     const float* __restrict__ al,
                                     const float* __restrict__ ar,
                                     const uint4* __restrict__ hbf,
                                     int lds_slot[4][64], float lds_ex[4][512],
                                     float acc[8]) {
#pragma unroll
  for (int k = 0; k < 8; ++k) acc[k] = 0.f;
  int deg = cnt[dst];
  if (deg > CAP) deg = CAP;
  if (deg == 0) return;
  __threadfence_block();
  if (lane < deg) {
    int s = slots[(size_t)dst * CAP + lane];
    lds_slot[wave][lane] = s;
    float4 a0 = *(const float4*)(al + (size_t)s * 8);
    float4 a1 = *(const float4*)(al + (size_t)s * 8 + 4);
    float4 r0 = *(const float4*)(ar + (size_t)dst * 8);
    float4 r1 = *(const float4*)(ar + (size_t)dst * 8 + 4);
    float* exq = &lds_ex[wave][lane * 8];
    exq[0] = __expf(leaky(a0.x + r0.x));
    exq[1] = __expf(leaky(a0.y + r0.y));
    exq[2] = __expf(leaky(a0.z + r0.z));
    exq[3] = __expf(leaky(a0.w + r0.w));
    exq[4] = __expf(leaky(a1.x + r1.x));
    exq[5] = __expf(leaky(a1.y + r1.y));
    exq[6] = __expf(leaky(a1.z + r1.z));
    exq[7] = __expf(leaky(a1.w + r1.w));
  }
  __threadfence_block();
  float den = 0.f;
  int iters = (deg + 1) >> 1;
  for (int it = 0; it < iters; ++it) {
    int j = it * 2 + h;
    if (j < deg) {
      int sj = lds_slot[wave][j];
      float w = lds_ex[wave][j * 8 + head];
      uint4 u = hbf[(size_t)sj * 32 + sub];
      den += w;
      float f[8];
      bf8(u, f);
#pragma unroll
      for (int k = 0; k < 8; ++k) acc[k] += w * f[k];
    }
  }
#pragma unroll
  for (int k = 0; k < 8; ++k) acc[k] += __shfl_xor(acc[k], 32);
  den += __shfl_xor(den, 32);
  float inv = 1.f / den;
#pragma unroll
  for (int k = 0; k < 8; ++k) acc[k] *= inv;
}

// ---- fused: all relations + beta combine + ReLU, A and B node sets ----------
__global__ __launch_bounds__(256) void agg_combine(
    const int* __restrict__ cnt_ba, const int* __restrict__ sl_ba,
    const float* __restrict__ al1, const float* __restrict__ ar1,
    const int* __restrict__ cnt_aa, const int* __restrict__ sl_aa,
    const float* __restrict__ al2, const float* __restrict__ ar2,
    const int* __restrict__ cnt_ab, const int* __restrict__ sl_ab,
    const float* __restrict__ al0, const float* __restrict__ ar0,
    const uint4* __restrict__ hAbf, const uint4* __restrict__ hBbf,
    const float* __restrict__ rlA, const float* __restrict__ rrA,
    const float* __restrict__ rlB, const float* __restrict__ rrB,
    float* __restrict__ outp) {
  __shared__ int lds_slot[4][64];
  __shared__ float lds_ex[4][512];
  int wave = threadIdx.x >> 6, lane = threadIdx.x & 63;
  int h = lane >> 5, sub = lane & 31, head = sub >> 2;
  bool isA = blockIdx.x < (NAn / 4);
  int dst = (isA ? blockIdx.x : blockIdx.x - NAn / 4) * 4 + wave;
  float m0[8], hv[8], o[8];
  if (isA) {
    float m1[8];
    gat2(dst, wave, lane, h, sub, head, cnt_ba, sl_ba, al1, ar1, hBbf, lds_slot, lds_ex, m0);
    gat2(dst, wave, lane, h, sub, head, cnt_aa, sl_aa, al2, ar2, hAbf, lds_slot, lds_ex, m1);
    uint4 us = hAbf[(size_t)dst * 32 + sub];
    bf8(us, hv);
    const float4* rl4 = (const float4*)rlA;
    const float4* rr4 = (const float4*)rrA;
    float4 rl0 = rl4[sub * 2], rl1 = rl4[sub * 2 + 1];
    float4 rr0 = rr4[sub * 2], rr1 = rr4[sub * 2 + 1];
    float rl8[8] = {rl0.x, rl0.y, rl0.z, rl0.w, rl1.x, rl1.y, rl1.z, rl1.w};
    float rr8[8] = {rr0.x, rr0.y, rr0.z, rr0.w, rr1.x, rr1.y, rr1.z, rr1.w};
    float pbl = 0, p0 = 0, p1 = 0, p2 = 0;
#pragma unroll
    for (int k = 0; k < 8; ++k) {
      pbl += hv[k] * rl8[k];
      p0 += m0[k] * rr8[k];
      p1 += m1[k] * rr8[k];
      p2 += hv[k] * rr8[k];
    }
#pragma unroll
    for (int d = 1; d < 4; d <<= 1) {
      pbl += __shfl_xor(pbl, d);
      p0 += __shfl_xor(p0, d);
      p1 += __shfl_xor(p1, d);
      p2 += __shfl_xor(p2, d);
    }
    float b0 = leaky(pbl + p0), b1 = leaky(pbl + p1), b2 = leaky(pbl + p2);
    float mx = fmaxf(b0, fmaxf(b1, b2));
    float w0 = __expf(b0 - mx), w1 = __expf(b1 - mx), w2 = __expf(b2 - mx);
    float inv = 1.f / (w0 + w1 + w2);
    w0 *= inv; w1 *= inv; w2 *= inv;
#pragma unroll
    for (int k = 0; k < 8; ++k)
      o[k] = fmaxf(0.f, m0[k] * w0 + m1[k] * w1 + hv[k] * w2);
  } else {
    gat2(dst, wave, lane, h, sub, head, cnt_ab, sl_ab, al0, ar0, hAbf, lds_slot, lds_ex, m0);
    uint4 us = hBbf[(size_t)dst * 32 + sub];
    bf8(us, hv);
    const float4* rl4 = (const float4*)rlB;
    const float4* rr4 = (const float4*)rrB;
    float4 rl0 = rl4[sub * 2], rl1 = rl4[sub * 2 + 1];
    float4 rr0 = rr4[sub * 2], rr1 = rr4[sub * 2 + 1];
    float rl8[8] = {rl0.x, rl0.y, rl0.z, rl0.w, rl1.x, rl1.y, rl1.z, rl1.w};
    float rr8[8] = {rr0.x, rr0.y, rr0.z, rr0.w, rr1.x, rr1.y, rr1.z, rr1.w};
    float pbl = 0, p0 = 0, p1 = 0;
#pragma unroll
    for (int k = 0; k < 8; ++k) {
      pbl += hv[k] * rl8[k];
      p0 += m0[k] * rr8[k];
      p1 += hv[k] * rr8[k];
    }
#pragma unroll
    for (int d = 1; d < 4; d <<= 1) {
      pbl += __shfl_xor(pbl, d);
      p0 += __shfl_xor(p0, d);
      p1 += __shfl_xor(p1, d);
    }
    float b0 = leaky(pbl + p0), b1 = leaky(pbl + p1);
    float mx = fmaxf(b0, b1);
    float w0 = __expf(b0 - mx), w1 = __expf(b1 - mx);
    float inv = 1.f / (w0 + w1);
    w0 *= inv; w1 *= inv;
#pragma unroll
    for (int k = 0; k < 8; ++k) o[k] = fmaxf(0.f, m0[k] * w0 + hv[k] * w1);
  }
  float* orow = outp + (size_t)(isA ? dst : NAn + dst) * DOUT + sub * 8;
  if (h == 0) {
    *(float4*)orow = (float4){o[0], o[1], o[2], o[3]};
    *(float4*)(orow + 4) = (float4){o[4], o[5], o[6], o[7]};
  }
}

extern "C" void kernel_launch(void* const* d_in, const int* in_sizes, int n_in, void* d_out,
                              int out_size, void* d_ws, size_t ws_size, hipStream_t stream) {
  const float* xA = (const float*)d_in[0];
  const float* xB = (const float*)d_in[1];
  const int* e_ab = (const int*)d_in[2];
  const int* e_ba = (const int*)d_in[3];
  const int* e_aa = (const int*)d_in[4];
  const float* WA = (const float*)d_in[5];
  const float* bA = (const float*)d_in[6];
  const float* WB = (const float*)d_in[7];
  const float* bB = (const float*)d_in[8];
  const float* attn_l = (const float*)d_in[9];
  const float* attn_r = (const float*)d_in[10];
  const float* rlA = (const float*)d_in[11];
  const float* rrA = (const float*)d_in[12];
  const float* rlB = (const float*)d_in[13];
  const float* rrB = (const float*)d_in[14];
  float* out = (float*)d_out;

  char* p = (char*)d_ws;
  auto alloc = [&](size_t bytes) -> char* {
    char* r = p;
    p += (bytes + 255) & ~(size_t)255;
    return r;
  };
  unsigned* hAbf = (unsigned*)alloc((size_t)NAn * DOUT * 2);
  unsigned* hBbf = (unsigned*)alloc((size_t)NBn * DOUT * 2);
  float* al0 = (float*)alloc((size_t)NAn * NH * 4);
  float* ar1 = (float*)alloc((size_t)NAn * NH * 4);
  float* al2 = (float*)alloc((size_t)NAn * NH * 4);
  float* ar2 = (float*)alloc((size_t)NAn * NH * 4);
  float* ar0 = (float*)alloc((size_t)NBn * NH * 4);
  float* al1 = (float*)alloc((size_t)NBn * NH * 4);
  short8* WAhi = (short8*)alloc((size_t)8192 * 16);
  short8* WBhi = (short8*)alloc((size_t)8192 * 16);
  int* cnts = (int*)alloc((size_t)3 * NAn * 4);
  int* cnt_ba = cnts;
  int* cnt_aa = cnts + NAn;
  int* cnt_ab = cnts + 2 * NAn;
  int* slots_ba = (int*)alloc((size_t)NAn * CAP * 4);
  int* slots_aa = (int*)alloc((size_t)NAn * CAP * 4);
  int* slots_ab = (int*)alloc((size_t)NBn * CAP * 4);

  hipMemsetAsync(cnts, 0, (size_t)3 * NAn * 4, stream);

  wswz<<<64, 256, 0, stream>>>(WA, WB, WAhi, WBhi);
  build_csr3<<<(3 * NE + 255) / 256, 256, 0, stream>>>(e_ba, e_aa, e_ab, cnt_ba, cnt_aa,
                                                       cnt_ab, slots_ba, slots_aa, slots_ab);
  gemm_mfma<<<(NAn + NBn) / 64, 256, 0, stream>>>(xA, xB, WAhi, WBhi, bA, bB, hAbf, hBbf);
  alphas<<<((NAn + NBn) * NH + 255) / 256, 256, 0, stream>>>(
      (const uint2*)hAbf, (const uint2*)hBbf, attn_l, attn_r, al0, ar1, al2, ar2, ar0, al1);
  agg_combine<<<(NAn + NBn) / 4, 256, 0, stream>>>(
      cnt_ba, slots_ba, al1, ar1, cnt_aa, slots_aa, al2, ar2, cnt_ab, slots_ab, al0, ar0,
      (const uint4*)hAbf, (const uint4*)hBbf, rlA, rrA, rlB, rrB, out);
}